// Round 1
// baseline (162.873 us; speedup 1.0000x reference)
//
#include <hip/hip_runtime.h>
#include <math.h>

// EfficientGCN preprocess:
//   x: (N=128, C=3, T=300, V=25, M=2) fp32
//   out: (N, 3, 2C=6, T, V, M) fp32
// Branch 0 (joint):   [x ; x - x[:, :, :, 1, :]]
// Branch 1 (velocity):[x[t+1]-x[t] ; x[t+2]-x[t]] for t<T-2 else 0
// Branch 2 (bone):    bv = x - x[parent]; [bv ; acos(bv / (||bv||+1e-4))]

#define NN 128
#define CC 3
#define TT 300
#define VV 25
#define MM 2

constexpr int TVM  = TT * VV * MM;   // 15000 floats per (n,c) plane
constexpr int TV   = TT * VV;        // 7500 float2 per (n,c) plane
constexpr int OUTP = 3 * 6 * TVM;    // floats per n in output

__global__ __launch_bounds__(256)
void egcn_pre_kernel(const float* __restrict__ x,
                     const int* __restrict__ conn,
                     float* __restrict__ out) {
    int j = blockIdx.x * blockDim.x + threadIdx.x;   // one thread per (n,t,v), handles m=0,1 as float2
    if (j >= NN * TV) return;

    int n  = j / TV;
    int rv = j - n * TV;       // t*V + v  == float2 index within a (n,c) plane
    int t  = rv / VV;
    int v  = rv - t * VV;

    int pv = conn[v];
    bool hasvel = (t < TT - 2);

    const float* xn = x + (size_t)n * CC * TVM;

    float2 xv[3], xc[3], xp[3], x1[3], x2[3];
    #pragma unroll
    for (int c = 0; c < 3; ++c) {
        const float2* p2 = reinterpret_cast<const float2*>(xn + c * TVM);
        xv[c] = p2[rv];                 // this joint
        xc[c] = p2[t * VV + 1];         // center joint (v=1)
        xp[c] = p2[t * VV + pv];        // parent joint
        if (hasvel) {
            x1[c] = p2[rv + VV];        // t+1
            x2[c] = p2[rv + 2 * VV];    // t+2
        } else {
            x1[c] = make_float2(0.f, 0.f);
            x2[c] = make_float2(0.f, 0.f);
        }
    }

    // bone vectors + per-(m) length
    float2 bv[3];
    float ss0 = 0.f, ss1 = 0.f;
    #pragma unroll
    for (int c = 0; c < 3; ++c) {
        bv[c].x = xv[c].x - xp[c].x;
        bv[c].y = xv[c].y - xp[c].y;
        ss0 += bv[c].x * bv[c].x;
        ss1 += bv[c].y * bv[c].y;
    }
    float inv0 = 1.0f / (sqrtf(ss0) + 1e-4f);
    float inv1 = 1.0f / (sqrtf(ss1) + 1e-4f);

    float2* outn = reinterpret_cast<float2*>(out + (size_t)n * OUTP);

    #pragma unroll
    for (int c = 0; c < 3; ++c) {
        // branch 0: joint
        float2 rel = make_float2(xv[c].x - xc[c].x, xv[c].y - xc[c].y);
        outn[(0 * 6 + c)     * TV + rv] = xv[c];
        outn[(0 * 6 + c + 3) * TV + rv] = rel;

        // branch 1: velocity
        float2 v1 = hasvel ? make_float2(x1[c].x - xv[c].x, x1[c].y - xv[c].y)
                           : make_float2(0.f, 0.f);
        float2 v2 = hasvel ? make_float2(x2[c].x - xv[c].x, x2[c].y - xv[c].y)
                           : make_float2(0.f, 0.f);
        outn[(1 * 6 + c)     * TV + rv] = v1;
        outn[(1 * 6 + c + 3) * TV + rv] = v2;

        // branch 2: bone
        float2 ang = make_float2(acosf(bv[c].x * inv0), acosf(bv[c].y * inv1));
        outn[(2 * 6 + c)     * TV + rv] = bv[c];
        outn[(2 * 6 + c + 3) * TV + rv] = ang;
    }
}

extern "C" void kernel_launch(void* const* d_in, const int* in_sizes, int n_in,
                              void* d_out, int out_size, void* d_ws, size_t ws_size,
                              hipStream_t stream) {
    const float* x   = (const float*)d_in[0];
    const int* conn  = (const int*)d_in[1];
    float* out       = (float*)d_out;

    int total = NN * TV;                  // 960,000 threads
    int block = 256;
    int grid  = (total + block - 1) / block;
    egcn_pre_kernel<<<grid, block, 0, stream>>>(x, conn, out);
}